// Round 12
// baseline (104.888 us; speedup 1.0000x reference)
//
#include <hip/hip_runtime.h>
#include <cstdint>
#include <cstddef>

#define BB 8
#define CC 128
#define HH 96
#define WW 320
#define HW (HH*WW)        // 30720
#define NSEL 32
#define NSELH 16
#define OUTERS 6          // 6 * 1280 f4 = 7680 f4 = one plane

typedef float f32x4 __attribute__((ext_vector_type(4)));

__device__ __forceinline__ float sigmoidf_(float x) {
  return __builtin_amdgcn_rcpf(1.0f + __expf(-x));
}

// K0: closed-form runs via 96-bit column bitmask + ctz. Mask-only input,
// so it can run BEFORE the big pass (kk feeds K1's fused max-diff).
__global__ __launch_bounds__(64) void k_runs(
    const int* __restrict__ mask, uint8_t* __restrict__ kk) {
  int b = blockIdx.x / 5;
  int w = (blockIdx.x % 5)*64 + threadIdx.x;
  const int* __restrict__ mcol = mask + (size_t)b*HW + w;
  unsigned long long lo=0ull, hi=0ull;
  #pragma unroll
  for (int h=0; h<64; ++h) lo |= (unsigned long long)(mcol[h*WW]!=0) << h;
  #pragma unroll
  for (int h=64; h<95; ++h) hi |= (unsigned long long)(mcol[h*WW]!=0) << (h-64);
  uint8_t* __restrict__ kcol = kk + (size_t)b*HW + w;
  #pragma unroll
  for (int h=0; h<96; ++h) {
    unsigned long long s;
    if (h == 0)      s = lo;
    else if (h < 64) s = (lo >> h) | (hi << (64-h));
    else             s = hi >> (h-64);
    int run = __builtin_ctzll(~s | (1ull<<33));
    kcol[h*WW] = (uint8_t)(run > 32 ? 32 : run);
  }
}

// K1: one block per plane. Copy x->out + T/A/Q sums + per-plane max|prop-sel|
// fused into the single streaming pass. Descending outer order keeps gather
// targets (rows h..h+32) in the just-streamed, L1/L2-warm window.
__global__ __launch_bounds__(256) void k_copy_reduce_max(
    const float* __restrict__ x, float* __restrict__ out,
    const uint8_t* __restrict__ kk,
    double* __restrict__ partials, float* __restrict__ pmax) {
  int t = threadIdx.x;
  int bc = blockIdx.x;              // 0..1023 = b*CC + c
  int b = bc >> 7;
  const float* __restrict__ xp = x + (size_t)bc * HW;
  const f32x4* __restrict__ xi = (const f32x4*)xp;
  f32x4* __restrict__ oi = (f32x4*)(out + (size_t)bc * HW);
  const uint8_t* __restrict__ kb = kk + (size_t)b*HW;
  float tf = 0.f, af = 0.f, qf = 0.f, mxf = 0.f;
  #pragma unroll 1
  for (int o = OUTERS-1; o >= 0; --o) {
    int base = o*1280;
    f32x4 v[5]; unsigned kv[5];
    #pragma unroll
    for (int u = 0; u < 5; ++u) {
      int j = base + u*256 + t;
      v[u] = xi[j];
      int h = j / 80, w4 = (j - h*80)*4;
      kv[u] = *(const unsigned*)(kb + h*WW + w4);   // 4 run-lengths
    }
    __builtin_amdgcn_sched_barrier(0);   // keep the 5+5 loads batched
    #pragma unroll
    for (int u = 0; u < 5; ++u) oi[base + u*256 + t] = v[u];
    #pragma unroll
    for (int u = 0; u < 5; ++u) {
      int j = base + u*256 + t;
      int h = j / 80, w4 = (j - h*80)*4;
      unsigned k4 = kv[u];
      // gathers hit rows streamed this or previous (descending) outer -> warm
      float p0 = xp[(h + (int)(k4       & 0xffu))*WW + w4 + 0];
      float p1 = xp[(h + (int)((k4>>8)  & 0xffu))*WW + w4 + 1];
      float p2 = xp[(h + (int)((k4>>16) & 0xffu))*WW + w4 + 2];
      float p3 = xp[(h + (int)( k4>>24        ))*WW + w4 + 3];
      mxf = fmaxf(mxf, fmaxf(fmaxf(fabsf(p0-v[u].x), fabsf(p1-v[u].y)),
                             fmaxf(fabsf(p2-v[u].z), fabsf(p3-v[u].w))));
      float d = 0.1f + (float)h * (0.9f/95.0f);
      float s0 = sigmoidf_(v[u].x), s1 = sigmoidf_(v[u].y);
      float s2 = sigmoidf_(v[u].z), s3 = sigmoidf_(v[u].w);
      float ts = (s0+s1)+(s2+s3);
      tf += ts;
      af += ts * d;
      qf += (s0*s0+s1*s1)+(s2*s2+s3*s3);
    }
  }
  __shared__ double sh[3][256];
  __shared__ float shm[256];
  sh[0][t]=(double)tf; sh[1][t]=(double)af; sh[2][t]=(double)qf; shm[t]=mxf;
  __syncthreads();
  for (int ofs=128; ofs>0; ofs>>=1) {
    if (t < ofs) {
      sh[0][t]+=sh[0][t+ofs];
      sh[1][t]+=sh[1][t+ofs];
      sh[2][t]+=sh[2][t+ofs];
      shm[t] = fmaxf(shm[t], shm[t+ofs]);
    }
    __syncthreads();
  }
  if (t==0) {
    partials[bc*3+0]=sh[0][0];
    partials[bc*3+1]=sh[1][0];
    partials[bc*3+2]=sh[2][0];
    pmax[bc]=shm[0];
  }
}

// K2: rank channels, emit idx[32] and per-(b,slot) mclip (0.3*max, 0->1).
__global__ __launch_bounds__(CC) void k_select(
    const double* __restrict__ partials, const float* __restrict__ pmax,
    int* __restrict__ idx, float* __restrict__ smc) {
  int c = threadIdx.x;
  double T=0.0, A=0.0, Q=0.0;
  for (int b=0;b<BB;b++) {
    int p = b*CC + c;
    T += partials[p*3+0];
    A += partials[p*3+1];
    Q += partials[p*3+2];
  }
  double sn = sqrt(Q); if (sn < 1e-6) sn = 1e-6;
  double c1 = A / sn;
  double c2 = (T - A) / sn;
  __shared__ double s1[CC], s2[CC];
  s1[c]=c1; s2[c]=c2;
  __syncthreads();
  int r1=0, r2=0;
  for (int j=0;j<CC;j++) {
    r1 += (s1[j] > c1) || (s1[j]==c1 && j<c);
    r2 += (s2[j] > c2) || (s2[j]==c2 && j<c);
  }
  if (r1 < NSELH || r2 < NSELH) {
    for (int b=0;b<BB;b++) {
      float m = pmax[b*CC + c] * 0.3f;
      if (m == 0.0f) m = 1.0f;
      if (r1 < NSELH) smc[b*NSEL + r1] = m;
      if (r2 < NSELH) smc[b*NSEL + NSELH + r2] = m;
    }
  }
  if (r1 < NSELH) idx[r1] = c;
  if (r2 < NSELH) idx[NSELH + r2] = c;
}

// K3: w = max_c clip(|prop-sel|/mclip_c,0,1); refined = w*prop + (1-w)*sel.
__global__ __launch_bounds__(WW) void k_refine(
    const float* __restrict__ x, const int* __restrict__ idx,
    const uint8_t* __restrict__ kk, const float* __restrict__ smcin,
    float* __restrict__ out) {
  int bh = blockIdx.x;
  int b = bh / HH, h = bh - b*HH;
  int w = threadIdx.x;
  __shared__ int sidx[NSEL];
  __shared__ float smc[NSEL];
  if (threadIdx.x < NSEL) {
    sidx[threadIdx.x] = idx[threadIdx.x];
    smc[threadIdx.x]  = smcin[b*NSEL + threadIdx.x];
  }
  __syncthreads();
  int r = h + (int)kk[(size_t)bh*WW + w];
  float sel[NSEL], prop[NSEL];
  float wmax = 0.0f;
  #pragma unroll
  for (int c=0;c<NSEL;c++) {
    const float* __restrict__ base = x + ((size_t)b*CC + sidx[c])*HW;
    sel[c]  = base[h*WW + w];
    prop[c] = base[r*WW + w];
    float v = fabsf(prop[c]-sel[c]) / smc[c];
    wmax = fmaxf(wmax, fminf(v, 1.0f));
  }
  #pragma unroll
  for (int c=0;c<NSEL;c++) {
    float rf = wmax*prop[c] + (1.0f - wmax)*sel[c];
    out[((size_t)b*CC + sidx[c])*HW + h*WW + w] = rf;
  }
}

extern "C" void kernel_launch(void* const* d_in, const int* in_sizes, int n_in,
                              void* d_out, int out_size, void* d_ws, size_t ws_size,
                              hipStream_t stream) {
  const float* x   = (const float*)d_in[0];
  const int* mask  = (const int*)d_in[1];
  float* out       = (float*)d_out;

  char* ws = (char*)d_ws;
  double* partials = (double*)(ws);                 // 1024*3*8 = 24576 B
  float*  pmax     = (float*)(ws + 24576);          // 4096 B
  int*    idx      = (int*)(ws + 24576 + 4096);     // 128 B
  float*  smc      = (float*)(ws + 24576 + 4096 + 128);   // 1024 B
  uint8_t* kk      = (uint8_t*)(ws + 24576 + 4096 + 128 + 1024); // 245760 B

  k_runs<<<BB*5, 64, 0, stream>>>(mask, kk);
  k_copy_reduce_max<<<BB*CC, 256, 0, stream>>>(x, out, kk, partials, pmax);
  k_select<<<1, CC, 0, stream>>>(partials, pmax, idx, smc);
  k_refine<<<BB*HH, WW, 0, stream>>>(x, idx, kk, smc, out);
}